// Round 10
// baseline (1589.803 us; speedup 1.0000x reference)
//
#include <hip/hip_runtime.h>
#include <cmath>

// ---------------- problem constants ----------------
constexpr int N = 20000, T = 13, E = 320000;
typedef unsigned int uint32;

// ---------------- bf16 helpers (manual, branch-free) ----------------
__device__ __forceinline__ unsigned short f2bf(float f) {
  unsigned int u = __float_as_uint(f);
  unsigned int r = (u + 0x7FFFu + ((u >> 16) & 1u)) >> 16;
  return (unsigned short)r;
}
__device__ __forceinline__ float bflo(uint32 v) { return __uint_as_float(v << 16); }
__device__ __forceinline__ float bfhi(uint32 v) { return __uint_as_float(v & 0xFFFF0000u); }
__device__ __forceinline__ uint32 packbf(float lo, float hi) {
  return (uint32)f2bf(lo) | ((uint32)f2bf(hi) << 16);
}

// ---------------- workspace layout ----------------
constexpr size_t WALIGN = 512;
constexpr size_t align_up(size_t x) { return (x + WALIGN - 1) & ~(WALIGN - 1); }

constexpr size_t XA_OFF  = 0;
constexpr size_t X_SZ    = align_up((size_t)N * 13 * 32 * 4);   // oversized (bf16 uses half)
constexpr size_t XB_OFF  = XA_OFF + X_SZ;
constexpr size_t H_OFF   = XB_OFF + X_SZ;
constexpr size_t H_SZ    = align_up((size_t)N * 12 * 32 * 4);   // oversized (bf16 uses half)
constexpr size_t C1_OFF  = H_OFF + H_SZ;
constexpr size_t C2_OFF  = C1_OFF + H_SZ;
constexpr size_t C3_OFF  = C2_OFF + H_SZ;
constexpr size_t HL_OFF  = C3_OFF + H_SZ;
constexpr size_t HL_SZ   = align_up((size_t)N * 256 * 4);
constexpr size_t WS2_OFF = HL_OFF + HL_SZ;                 // skip_w transposed 256x256
constexpr size_t SB_OFF  = WS2_OFF + align_up(256 * 256 * 4);
constexpr size_t SUMS_OFF = SB_OFF + align_up(256 * 4);    // 8 layers x 64 floats
constexpr size_t PAR_OFF  = SUMS_OFF + align_up(8 * 64 * 4); // 9 slots x 64 floats
constexpr size_t CNT_OFF  = PAR_OFF + align_up(9 * 64 * 4);
constexpr size_t ROW_OFF  = CNT_OFF + align_up((size_t)N * 4);
constexpr size_t FILL_OFF = ROW_OFF + align_up((size_t)(N + 1) * 4);
constexpr size_t COL_OFF  = FILL_OFF + align_up((size_t)N * 4);
constexpr size_t DEG_OFF  = COL_OFF + align_up((size_t)E * 4);
// aliases used after all layers are done:
constexpr size_t S_OFF  = C2_OFF;   // N*256 floats
constexpr size_t Y1_OFF = H_OFF;    // N*512 floats (spans H+C1)

// ---------------- CSR build ----------------
__global__ void k_count(const int* __restrict__ dst, int* __restrict__ cnt) {
  int i = blockIdx.x * 256 + threadIdx.x;
  if (i < E) atomicAdd(&cnt[dst[i]], 1);
}

__global__ __launch_bounds__(256) void k_scan(const int* __restrict__ cnt, int* __restrict__ rowptr,
                                              int* __restrict__ fill, float* __restrict__ deginv) {
  __shared__ int sc[256];
  int tid = threadIdx.x;
  constexpr int CH = (N + 255) / 256;
  int start = tid * CH;
  int s = 0;
  for (int i = 0; i < CH; i++) { int idx = start + i; if (idx < N) s += cnt[idx]; }
  sc[tid] = s; __syncthreads();
  for (int off = 1; off < 256; off <<= 1) {
    int v = (tid >= off) ? sc[tid - off] : 0;
    __syncthreads();
    sc[tid] += v;
    __syncthreads();
  }
  int run = (tid == 0) ? 0 : sc[tid - 1];
  for (int i = 0; i < CH; i++) {
    int idx = start + i;
    if (idx < N) {
      int v = cnt[idx];
      rowptr[idx] = run; fill[idx] = run;
      deginv[idx] = 1.0f / (float)(v > 1 ? v : 1);
      run += v;
    }
  }
  if (tid == 255) rowptr[N] = run;
}

__global__ void k_scatter(const int* __restrict__ src, const int* __restrict__ dst,
                          int* __restrict__ fill, int* __restrict__ col) {
  int i = blockIdx.x * 256 + threadIdx.x;
  if (i < E) { int d = dst[i]; int p = atomicAdd(&fill[d], 1); col[p] = src[i]; }
}

__global__ void k_init_params(float* __restrict__ par) {
  int i = threadIdx.x;                 // 64 threads: slot 0 = identity affine
  par[i] = (i < 32) ? 1.0f : 0.0f;
}

// ---------------- enter 1x1 conv: inputs [N,T,3] -> x bf16 [n][t][c] ----------------
__global__ void k_enter(const float* __restrict__ in, const float* __restrict__ w,
                        const float* __restrict__ b, uint32* __restrict__ x) {
  int idx = blockIdx.x * 256 + threadIdx.x;     // word index; word = 2 channels
  if (idx >= N * 13 * 16) return;
  int cw = idx & 15; int tmp = idx >> 4; int t = tmp % 13; int n = tmp / 13;
  int c0 = cw * 2;
  const float* ip = in + (size_t)n * (13 * 3) + t * 3;
  float v0 = b[c0]     + w[c0 * 3 + 0]       * ip[0] + w[c0 * 3 + 1]       * ip[1] + w[c0 * 3 + 2]       * ip[2];
  float v1 = b[c0 + 1] + w[(c0 + 1) * 3 + 0] * ip[0] + w[(c0 + 1) * 3 + 1] * ip[1] + w[(c0 + 1) * 3 + 2] * ip[2];
  x[idx] = packbf(v0, v1);
}

// ---------------- gated dilated conv: x bf16 in (affine on load), h bf16 out (+ hlast fp32) ----------------
template <int TIN, int TOUT, int D>
__global__ __launch_bounds__(256, 4) void k_conv(const uint32* __restrict__ x,
    const float* __restrict__ fw, const float* __restrict__ fb,
    const float* __restrict__ gw, const float* __restrict__ gb,
    const float* __restrict__ par, int slot, int layer,
    unsigned short* __restrict__ h, float* __restrict__ hlast) {
  __shared__ float wf[64 * 33], wg[64 * 33];      // [2i+k][o] padded stride 33
  __shared__ float xs[8][TIN * 32];
  int tx = threadIdx.x, ty = threadIdx.y;
  int tid = ty * 32 + tx;
  const float* fwl = fw + (size_t)layer * 2048;   // [o][i][k] linear = o*64 + 2i + k
  const float* gwl = gw + (size_t)layer * 2048;
  for (int i = tid; i < 2048; i += 256) {
    int o = i >> 6, r = i & 63;
    wf[r * 33 + o] = fwl[i];
    wg[r * 33 + o] = gwl[i];
  }
  int n0 = blockIdx.x * 8;
  const float* scp = par + slot * 64;
  for (int i = tid; i < 8 * TIN * 16; i += 256) {   // word granularity (2ch/word)
    int nl = i / (TIN * 16), rem = i % (TIN * 16);
    int cw = rem & 15; int c0 = cw * 2;
    int gn = n0 + nl;
    uint32 v = (gn < N) ? x[(size_t)gn * (TIN * 16) + rem] : 0u;
    int off = (rem >> 4) * 32 + c0;                 // t*32 + c
    float f0 = (gn < N) ? (scp[c0] * bflo(v) + scp[32 + c0]) : 0.0f;
    float f1 = (gn < N) ? (scp[c0 + 1] * bfhi(v) + scp[32 + c0 + 1]) : 0.0f;
    xs[nl][off] = f0;
    xs[nl][off + 1] = f1;
  }
  __syncthreads();
  int o = tx, nn = ty, n = n0 + nn;
  float accF[TOUT], accG[TOUT];
  float fbv = fb[layer * 32 + o], gbv = gb[layer * 32 + o];
#pragma unroll
  for (int t = 0; t < TOUT; t++) { accF[t] = fbv; accG[t] = gbv; }
#pragma unroll 4
  for (int i = 0; i < 32; i++) {
    float xv[TIN];
#pragma unroll
    for (int t = 0; t < TIN; t++) xv[t] = xs[nn][t * 32 + i];
    float w0 = wf[(2 * i) * 33 + o], w1 = wf[(2 * i + 1) * 33 + o];
    float g0 = wg[(2 * i) * 33 + o], g1 = wg[(2 * i + 1) * 33 + o];
#pragma unroll
    for (int t = 0; t < TOUT; t++) {
      accF[t] += w0 * xv[t] + w1 * xv[t + D];
      accG[t] += g0 * xv[t] + g1 * xv[t + D];
    }
  }
  if (n < N) {
#pragma unroll
    for (int t = 0; t < TOUT; t++) {
      float f = accF[t];
      float af = fabsf(f);
      float ef = __expf(-2.0f * af);
      float th = (1.0f - ef) / (1.0f + ef);
      th = copysignf(th, f);
      float sg = 1.0f / (1.0f + __expf(-accG[t]));
      float hv = th * sg;
      h[(size_t)n * (TOUT * 32) + t * 32 + o] = f2bf(hv);
      if (t == TOUT - 1) hlast[(size_t)n * 256 + layer * 32 + o] = hv;
    }
  }
}

// ---------------- one diffusion hop (bf16, fp32 accumulate, x8 edge unroll) ----------------
template <int F>
__global__ __launch_bounds__(256) void k_hop(const uint32* __restrict__ in, uint32* __restrict__ out,
    const int* __restrict__ rowptr, const int* __restrict__ col, const float* __restrict__ deginv) {
  constexpr int F2 = F / 2;                 // uint words per row
  constexpr int NW = (F2 + 63) / 64;
  int wid = (blockIdx.x * 256 + threadIdx.x) >> 6;   // one wave per node
  int lane = threadIdx.x & 63;
  if (wid >= N) return;
  int s = rowptr[wid], e = rowptr[wid + 1];
  float alo[NW], ahi[NW];
#pragma unroll
  for (int k = 0; k < NW; k++) { alo[k] = 0.0f; ahi[k] = 0.0f; }
  int idx = s;
  for (; idx + 7 < e; idx += 8) {
    const uint32* p[8];
#pragma unroll
    for (int q = 0; q < 8; q++) p[q] = in + (size_t)col[idx + q] * F2;
    uint32 v[8][NW];
#pragma unroll
    for (int q = 0; q < 8; q++) {
#pragma unroll
      for (int k = 0; k < NW; k++) {
        int j = k * 64 + lane;
        v[q][k] = (j < F2) ? p[q][j] : 0u;
      }
    }
#pragma unroll
    for (int k = 0; k < NW; k++) {
      alo[k] += ((bflo(v[0][k]) + bflo(v[1][k])) + (bflo(v[2][k]) + bflo(v[3][k]))) +
                ((bflo(v[4][k]) + bflo(v[5][k])) + (bflo(v[6][k]) + bflo(v[7][k])));
      ahi[k] += ((bfhi(v[0][k]) + bfhi(v[1][k])) + (bfhi(v[2][k]) + bfhi(v[3][k]))) +
                ((bfhi(v[4][k]) + bfhi(v[5][k])) + (bfhi(v[6][k]) + bfhi(v[7][k])));
    }
  }
  for (; idx + 3 < e; idx += 4) {
    const uint32* p0 = in + (size_t)col[idx] * F2;
    const uint32* p1 = in + (size_t)col[idx + 1] * F2;
    const uint32* p2 = in + (size_t)col[idx + 2] * F2;
    const uint32* p3 = in + (size_t)col[idx + 3] * F2;
#pragma unroll
    for (int k = 0; k < NW; k++) {
      int j = k * 64 + lane;
      if (j < F2) {
        uint32 v0 = p0[j], v1 = p1[j], v2 = p2[j], v3 = p3[j];
        alo[k] += (bflo(v0) + bflo(v1)) + (bflo(v2) + bflo(v3));
        ahi[k] += (bfhi(v0) + bfhi(v1)) + (bfhi(v2) + bfhi(v3));
      }
    }
  }
  for (; idx < e; ++idx) {
    const uint32* p = in + (size_t)col[idx] * F2;
#pragma unroll
    for (int k = 0; k < NW; k++) {
      int j = k * 64 + lane;
      if (j < F2) { uint32 v = p[j]; alo[k] += bflo(v); ahi[k] += bfhi(v); }
    }
  }
  float inv = deginv[wid];
  uint32* q = out + (size_t)wid * F2;
#pragma unroll
  for (int k = 0; k < NW; k++) {
    int j = k * 64 + lane;
    if (j < F2) q[j] = packbf(alo[k] * inv, ahi[k] * inv);
  }
}

// ---------------- combine: bf16 sources + bf16 residual -> bf16 x out; k-loop fenced ----------------
template <int TIN, int TOUT>
__global__ __launch_bounds__(256) void k_combine(const uint32* __restrict__ h,
    const uint32* __restrict__ c1, const uint32* __restrict__ c2, const uint32* __restrict__ c3,
    const float* __restrict__ gcw, const float* __restrict__ gcb,
    const uint32* __restrict__ xcur, int layer,
    const float* __restrict__ par, int slot,
    uint32* __restrict__ xnext, float* __restrict__ sums) {
  constexpr int RS = 34;                 // LDS row stride (floats)
  __shared__ float ws[4096];             // [k][c][o]
  __shared__ float xst[128 * RS];        // staging
  __shared__ float pbuf[96];             // gcb[32], psc[32], psh[32]
  __shared__ float r1s[32], r2s[32];
  int tid = threadIdx.x;
  const float* wsrc = gcw + (size_t)layer * 4096;
  for (int i = tid; i < 4096; i += 256) ws[i] = wsrc[i];
  if (tid < 32) {
    pbuf[tid]      = gcb[layer * 32 + tid];
    pbuf[32 + tid] = par[slot * 64 + tid];
    pbuf[64 + tid] = par[slot * 64 + 32 + tid];
    r1s[tid] = 0.0f; r2s[tid] = 0.0f;
  }

  int nrows = N * TOUT;
  int base = blockIdx.x * 128;
  int rg = tid >> 3, oq = tid & 7;       // rg: 0..31, oq: 0..7 (outs oq*4..+4)

  float acc[4][4];
#pragma unroll
  for (int i = 0; i < 4; i++)
#pragma unroll
    for (int j = 0; j < 4; j++) acc[i][j] = 0.0f;

  const uint32* srcs[4] = { h, c1, c2, c3 };
#pragma unroll 1
  for (int k = 0; k < 4; k++) {
    const uint32* src = srcs[k];
    __syncthreads();                     // xst free (also covers r1s init on k==0)
    const uint4* gp = (const uint4*)src;  // one uint4 = 8 bf16 channels
#pragma unroll
    for (int it = 0; it < 2; it++) {
      int l = it * 256 + tid;            // 512 uint4 = 128 rows
      int g = base * 4 + l;
      uint4 v = make_uint4(0u, 0u, 0u, 0u);
      if (g < nrows * 4) v = gp[g];
      int rl = l >> 2, q4 = l & 3;
      float* dst = &xst[rl * RS + q4 * 8];
      dst[0] = bflo(v.x); dst[1] = bfhi(v.x);
      dst[2] = bflo(v.y); dst[3] = bfhi(v.y);
      dst[4] = bflo(v.z); dst[5] = bfhi(v.z);
      dst[6] = bflo(v.w); dst[7] = bfhi(v.w);
    }
    __syncthreads();
    const float* wk = &ws[k * 1024];
#pragma unroll 4
    for (int c2i = 0; c2i < 16; c2i++) {
      int c = c2i * 2;
      float4 w0 = *(const float4*)&wk[c * 32 + oq * 4];
      float4 w1 = *(const float4*)&wk[(c + 1) * 32 + oq * 4];
#pragma unroll
      for (int i = 0; i < 4; i++) {
        float2 xv = *(const float2*)&xst[(rg + 32 * i) * RS + c];
        acc[i][0] += xv.x * w0.x + xv.y * w1.x;
        acc[i][1] += xv.x * w0.y + xv.y * w1.y;
        acc[i][2] += xv.x * w0.z + xv.y * w1.z;
        acc[i][3] += xv.x * w0.w + xv.y * w1.w;
      }
    }
  }

  // stage residual rows (bf16, compile-time TOUT division for row -> (n,t))
  constexpr int toff = TIN - TOUT;
  __syncthreads();
  {
#pragma unroll
    for (int it = 0; it < 8; it++) {
      int l = it * 256 + tid;            // 128 rows x 16 words
      int rrow = base + (l >> 4);
      int w = l & 15;
      if (rrow < nrows) {
        int n = rrow / TOUT, t = rrow - n * TOUT;
        uint32 v = xcur[((size_t)n * TIN + toff + t) * 16 + w];
        int rl = l >> 4;
        xst[rl * RS + 2 * w]     = bflo(v);
        xst[rl * RS + 2 * w + 1] = bfhi(v);
      }
    }
  }
  __syncthreads();

  // vout = acc + gcb + psc*xr + psh; BN partials; write back into private xst slots
  float gb0 = pbuf[oq * 4 + 0], gb1 = pbuf[oq * 4 + 1], gb2 = pbuf[oq * 4 + 2], gb3 = pbuf[oq * 4 + 3];
  float sc0 = pbuf[32 + oq * 4 + 0], sc1 = pbuf[32 + oq * 4 + 1], sc2 = pbuf[32 + oq * 4 + 2], sc3 = pbuf[32 + oq * 4 + 3];
  float sh0 = pbuf[64 + oq * 4 + 0], sh1 = pbuf[64 + oq * 4 + 1], sh2 = pbuf[64 + oq * 4 + 2], sh3 = pbuf[64 + oq * 4 + 3];
  float s1[4] = {0.f, 0.f, 0.f, 0.f}, s2[4] = {0.f, 0.f, 0.f, 0.f};
#pragma unroll
  for (int i = 0; i < 4; i++) {
    int r = rg + 32 * i;
    bool act = (base + r) < nrows;
    float2 xa = *(const float2*)&xst[r * RS + oq * 4];
    float2 xb = *(const float2*)&xst[r * RS + oq * 4 + 2];
    float v0 = acc[i][0] + gb0 + sc0 * xa.x + sh0;
    float v1 = acc[i][1] + gb1 + sc1 * xa.y + sh1;
    float v2 = acc[i][2] + gb2 + sc2 * xb.x + sh2;
    float v3 = acc[i][3] + gb3 + sc3 * xb.y + sh3;
    *(float2*)&xst[r * RS + oq * 4]     = make_float2(v0, v1);
    *(float2*)&xst[r * RS + oq * 4 + 2] = make_float2(v2, v3);
    if (act) {
      s1[0] += v0; s1[1] += v1; s1[2] += v2; s1[3] += v3;
      s2[0] += v0 * v0; s2[1] += v1 * v1; s2[2] += v2 * v2; s2[3] += v3 * v3;
    }
  }
#pragma unroll
  for (int j = 0; j < 4; j++) {
    atomicAdd(&r1s[oq * 4 + j], s1[j]);
    atomicAdd(&r2s[oq * 4 + j], s2[j]);
  }
  __syncthreads();

  // cooperative coalesced output store (bf16)
  {
#pragma unroll
    for (int it = 0; it < 8; it++) {
      int l = it * 256 + tid;            // 128 rows x 16 words
      int g = base * 16 + l;
      if (g < nrows * 16) {
        int rl = l >> 4, w = l & 15;
        float lo = xst[rl * RS + 2 * w];
        float hi = xst[rl * RS + 2 * w + 1];
        xnext[g] = packbf(lo, hi);
      }
    }
  }
  if (tid < 32) atomicAdd(&sums[layer * 64 + tid], r1s[tid]);
  else if (tid < 64) atomicAdd(&sums[layer * 64 + tid], r2s[tid - 32]);
}

// ---------------- BN stats -> affine params for next slot ----------------
__global__ void k_bnfin(const float* __restrict__ sums, const float* __restrict__ bng,
                        const float* __restrict__ bnb, float* __restrict__ par,
                        int layer, int tout) {
  int o = threadIdx.x;  // 32
  float cnt = (float)N * (float)tout;
  float s1 = sums[layer * 64 + o], s2 = sums[layer * 64 + 32 + o];
  float mu = s1 / cnt;
  float var = s2 / cnt - mu * mu;
  float sc = bng[layer * 32 + o] * rsqrtf(var + 1e-5f);
  par[(layer + 1) * 64 + o] = sc;
  par[(layer + 1) * 64 + 32 + o] = bnb[layer * 32 + o] - mu * sc;
}

// ---------------- head prep ----------------
__global__ void k_prep_skipw(const float* __restrict__ sw, float* __restrict__ w2) {
  int idx = blockIdx.x * 256 + threadIdx.x;
  if (idx >= 8 * 256 * 32) return;
  int l = idx / (256 * 32), r = idx % (256 * 32), o = r / 32, c = r & 31;
  w2[o * 256 + l * 32 + c] = sw[idx];
}
__global__ void k_prep_sb(const float* __restrict__ sb, float* __restrict__ out) {
  int o = threadIdx.x;  // 256
  float s = 0.0f;
  for (int l = 0; l < 8; l++) s += sb[l * 256 + o];
  out[o] = s;
}

// ---------------- generic tiled fp32 GEMM: C[M,O] = act(A[M,K] @ W[O,K]^T + bias) ----------------
__global__ __launch_bounds__(256) void k_gemm(const float* __restrict__ A, const float* __restrict__ W,
    const float* __restrict__ bias, float* __restrict__ Cout,
    int M, int K, int Onum, int relu) {
  __shared__ float As[16][68];
  __shared__ float Wsh[16][68];
  int tid = threadIdx.x;
  int bm = blockIdx.x * 64, bo = blockIdx.y * 64;
  int tm = (tid >> 4) << 2, to = (tid & 15) << 2;
  float acc[4][4] = {};
  int lm = tid >> 2, kq = (tid & 3) << 2;
  for (int k0 = 0; k0 < K; k0 += 16) {
    float4 av = make_float4(0.f, 0.f, 0.f, 0.f);
    int gm = bm + lm;
    if (gm < M) av = *(const float4*)(A + (size_t)gm * K + k0 + kq);
    As[kq + 0][lm] = av.x; As[kq + 1][lm] = av.y; As[kq + 2][lm] = av.z; As[kq + 3][lm] = av.w;
    float4 wv = *(const float4*)(W + (size_t)(bo + lm) * K + k0 + kq);
    Wsh[kq + 0][lm] = wv.x; Wsh[kq + 1][lm] = wv.y; Wsh[kq + 2][lm] = wv.z; Wsh[kq + 3][lm] = wv.w;
    __syncthreads();
#pragma unroll
    for (int k = 0; k < 16; k++) {
      float am[4], wn[4];
#pragma unroll
      for (int j = 0; j < 4; j++) { am[j] = As[k][tm + j]; wn[j] = Wsh[k][to + j]; }
#pragma unroll
      for (int i = 0; i < 4; i++)
#pragma unroll
        for (int j = 0; j < 4; j++) acc[i][j] += am[i] * wn[j];
    }
    __syncthreads();
  }
#pragma unroll
  for (int i = 0; i < 4; i++) {
    int gm = bm + tm + i; if (gm >= M) continue;
#pragma unroll
    for (int j = 0; j < 4; j++) {
      int go = bo + to + j;
      float v = acc[i][j] + bias[go];
      if (relu) v = fmaxf(v, 0.0f);
      Cout[(size_t)gm * Onum + go] = v;
    }
  }
}

// ---------------- final: K-split tiled GEMM with atomic reduce -> d_out [N,24] ----------------
__global__ __launch_bounds__(256) void k_final2(const float* __restrict__ Y1, const float* __restrict__ W2,
                                                const float* __restrict__ b2, float* __restrict__ out) {
  __shared__ float y1s[64][68];
  __shared__ float w2s[24][65];
  int tid = threadIdx.x;
  int bm = blockIdx.x * 64;
  int k0 = blockIdx.y * 64;
  for (int i = tid; i < 64 * 16; i += 256) {
    int r = i >> 4, k4 = i & 15;
    int gm = bm + r;
    float4 v = make_float4(0.f, 0.f, 0.f, 0.f);
    if (gm < N) v = *(const float4*)(Y1 + (size_t)gm * 512 + k0 + k4 * 4);
    y1s[r][k4 * 4 + 0] = v.x; y1s[r][k4 * 4 + 1] = v.y;
    y1s[r][k4 * 4 + 2] = v.z; y1s[r][k4 * 4 + 3] = v.w;
  }
  for (int i = tid; i < 24 * 16; i += 256) {
    int o = i >> 4, k4 = i & 15;
    float4 v = *(const float4*)(W2 + (size_t)o * 512 + k0 + k4 * 4);
    w2s[o][k4 * 4 + 0] = v.x; w2s[o][k4 * 4 + 1] = v.y;
    w2s[o][k4 * 4 + 2] = v.z; w2s[o][k4 * 4 + 3] = v.w;
  }
  __syncthreads();
  int rg = tid >> 5;        // 0..7 -> rows rg*8..+8
  int o = tid & 31;         // 0..31, active o<24
  if (o < 24) {
    float acc[8] = {};
    for (int kk = 0; kk < 64; kk++) {
      float w = w2s[o][kk];
#pragma unroll
      for (int i = 0; i < 8; i++) acc[i] += y1s[rg * 8 + i][kk] * w;
    }
    float bias = (blockIdx.y == 0) ? b2[o] : 0.0f;
#pragma unroll
    for (int i = 0; i < 8; i++) {
      int gm = bm + rg * 8 + i;
      if (gm < N) atomicAdd(&out[(size_t)gm * 24 + o], acc[i] + bias);
    }
  }
}

// ---------------- host side ----------------
struct Ptrs {
  const float *fw, *fb, *gw, *gb, *gcw, *gcb, *bng, *bnb;
  void *H, *C1, *C2, *C3;
  float *HL, *par, *sums;
  const int *row, *col;
  const float *deg;
};

template <int TIN, int TOUT, int D>
static void run_layer(int layer, bool last, const Ptrs& P, uint32*& xc, uint32*& xn, hipStream_t stream) {
  dim3 cb(32, 8);
  int blocks = (N + 7) / 8;
  k_conv<TIN, TOUT, D><<<blocks, cb, 0, stream>>>(xc, P.fw, P.fb, P.gw, P.gb, P.par, layer, layer,
                                                  (unsigned short*)P.H, P.HL);
  if (!last) {
    constexpr int F = TOUT * 32;
    int hb = (N * 64 + 255) / 256;
    k_hop<F><<<hb, 256, 0, stream>>>((const uint32*)P.H, (uint32*)P.C1, P.row, P.col, P.deg);
    k_hop<F><<<hb, 256, 0, stream>>>((const uint32*)P.C1, (uint32*)P.C2, P.row, P.col, P.deg);
    k_hop<F><<<hb, 256, 0, stream>>>((const uint32*)P.C2, (uint32*)P.C3, P.row, P.col, P.deg);
    int cblocks = (N * TOUT + 127) / 128;
    k_combine<TIN, TOUT><<<cblocks, 256, 0, stream>>>((const uint32*)P.H, (const uint32*)P.C1,
                                                      (const uint32*)P.C2, (const uint32*)P.C3,
                                                      P.gcw, P.gcb, xc, layer, P.par, layer, xn, P.sums);
    k_bnfin<<<1, 32, 0, stream>>>(P.sums, P.bng, P.bnb, P.par, layer, TOUT);
    uint32* tmp = xc; xc = xn; xn = tmp;
  }
}

extern "C" void kernel_launch(void* const* d_in, const int* in_sizes, int n_in,
                              void* d_out, int out_size, void* d_ws, size_t ws_size,
                              hipStream_t stream) {
  const float* inputs  = (const float*)d_in[0];
  const int*   esrc    = (const int*)d_in[1];
  const int*   edst    = (const int*)d_in[2];
  const float* enter_w = (const float*)d_in[3];
  const float* enter_b = (const float*)d_in[4];
  const float* filt_w  = (const float*)d_in[5];
  const float* filt_b  = (const float*)d_in[6];
  const float* gate_w  = (const float*)d_in[7];
  const float* gate_b  = (const float*)d_in[8];
  const float* gc_w    = (const float*)d_in[9];
  const float* gc_b    = (const float*)d_in[10];
  const float* skip_w  = (const float*)d_in[11];
  const float* skip_b  = (const float*)d_in[12];
  const float* bn_g    = (const float*)d_in[13];
  const float* bn_b    = (const float*)d_in[14];
  const float* out1_w  = (const float*)d_in[15];
  const float* out1_b  = (const float*)d_in[16];
  const float* out2_w  = (const float*)d_in[17];
  const float* out2_b  = (const float*)d_in[18];

  char* ws = (char*)d_ws;
  uint32* XA = (uint32*)(ws + XA_OFF);
  uint32* XB = (uint32*)(ws + XB_OFF);
  void* H    = (void*)(ws + H_OFF);
  void* C1   = (void*)(ws + C1_OFF);
  void* C2   = (void*)(ws + C2_OFF);
  void* C3   = (void*)(ws + C3_OFF);
  float* HL  = (float*)(ws + HL_OFF);
  float* WS2 = (float*)(ws + WS2_OFF);
  float* SB  = (float*)(ws + SB_OFF);
  float* SUMS = (float*)(ws + SUMS_OFF);
  float* PAR  = (float*)(ws + PAR_OFF);
  int* CNT  = (int*)(ws + CNT_OFF);
  int* ROW  = (int*)(ws + ROW_OFF);
  int* FILL = (int*)(ws + FILL_OFF);
  int* COL  = (int*)(ws + COL_OFF);
  float* DEG = (float*)(ws + DEG_OFF);
  float* S  = (float*)(ws + S_OFF);
  float* Y1 = (float*)(ws + Y1_OFF);

  hipMemsetAsync(CNT, 0, (size_t)N * 4, stream);
  hipMemsetAsync(SUMS, 0, 8 * 64 * 4, stream);
  hipMemsetAsync(d_out, 0, (size_t)out_size * 4, stream);

  k_count<<<(E + 255) / 256, 256, 0, stream>>>(edst, CNT);
  k_scan<<<1, 256, 0, stream>>>(CNT, ROW, FILL, DEG);
  k_scatter<<<(E + 255) / 256, 256, 0, stream>>>(esrc, edst, FILL, COL);
  k_init_params<<<1, 64, 0, stream>>>(PAR);
  k_enter<<<(N * 13 * 16 + 255) / 256, 256, 0, stream>>>(inputs, enter_w, enter_b, XA);
  k_prep_skipw<<<(8 * 256 * 32 + 255) / 256, 256, 0, stream>>>(skip_w, WS2);
  k_prep_sb<<<1, 256, 0, stream>>>(skip_b, SB);

  Ptrs P;
  P.fw = filt_w; P.fb = filt_b; P.gw = gate_w; P.gb = gate_b;
  P.gcw = gc_w; P.gcb = gc_b; P.bng = bn_g; P.bnb = bn_b;
  P.H = H; P.C1 = C1; P.C2 = C2; P.C3 = C3; P.HL = HL; P.par = PAR; P.sums = SUMS;
  P.row = ROW; P.col = COL; P.deg = DEG;

  uint32* xc = XA; uint32* xn = XB;
  run_layer<13, 12, 1>(0, false, P, xc, xn, stream);
  run_layer<12, 10, 2>(1, false, P, xc, xn, stream);
  run_layer<10, 9, 1>(2, false, P, xc, xn, stream);
  run_layer<9, 7, 2>(3, false, P, xc, xn, stream);
  run_layer<7, 6, 1>(4, false, P, xc, xn, stream);
  run_layer<6, 4, 2>(5, false, P, xc, xn, stream);
  run_layer<4, 3, 1>(6, false, P, xc, xn, stream);
  run_layer<3, 1, 2>(7, true, P, xc, xn, stream);

  // head: S = relu(HL @ WS2^T + SB); Y1 = relu(S @ out1_w^T + out1_b); out = Y1 @ out2_w^T + out2_b
  dim3 g1((N + 63) / 64, 256 / 64);
  k_gemm<<<g1, 256, 0, stream>>>(HL, WS2, SB, S, N, 256, 256, 1);
  dim3 g2((N + 63) / 64, 512 / 64);
  k_gemm<<<g2, 256, 0, stream>>>(S, out1_w, out1_b, Y1, N, 256, 512, 1);
  dim3 gf((N + 63) / 64, 8);
  k_final2<<<gf, 256, 0, stream>>>(Y1, out2_w, out2_b, (float*)d_out);
}

// Round 11
// 1533.986 us; speedup vs baseline: 1.0364x; 1.0364x over previous
//
#include <hip/hip_runtime.h>
#include <cmath>

// ---------------- problem constants ----------------
constexpr int N = 20000, T = 13, E = 320000;
typedef unsigned int uint32;

// ---------------- bf16 helpers (manual, branch-free) ----------------
__device__ __forceinline__ unsigned short f2bf(float f) {
  unsigned int u = __float_as_uint(f);
  unsigned int r = (u + 0x7FFFu + ((u >> 16) & 1u)) >> 16;
  return (unsigned short)r;
}
__device__ __forceinline__ float bflo(uint32 v) { return __uint_as_float(v << 16); }
__device__ __forceinline__ float bfhi(uint32 v) { return __uint_as_float(v & 0xFFFF0000u); }
__device__ __forceinline__ uint32 packbf(float lo, float hi) {
  return (uint32)f2bf(lo) | ((uint32)f2bf(hi) << 16);
}

// ---------------- workspace layout ----------------
constexpr size_t WALIGN = 512;
constexpr size_t align_up(size_t x) { return (x + WALIGN - 1) & ~(WALIGN - 1); }

constexpr size_t XA_OFF  = 0;
constexpr size_t X_SZ    = align_up((size_t)N * 13 * 32 * 4);   // oversized (bf16 uses half)
constexpr size_t XB_OFF  = XA_OFF + X_SZ;
constexpr size_t H_OFF   = XB_OFF + X_SZ;
constexpr size_t H_SZ    = align_up((size_t)N * 12 * 32 * 4);   // oversized (bf16 uses half)
constexpr size_t C1_OFF  = H_OFF + H_SZ;
constexpr size_t C2_OFF  = C1_OFF + H_SZ;
constexpr size_t C3_OFF  = C2_OFF + H_SZ;
constexpr size_t HL_OFF  = C3_OFF + H_SZ;
constexpr size_t HL_SZ   = align_up((size_t)N * 256 * 4);
constexpr size_t WS2_OFF = HL_OFF + HL_SZ;                 // skip_w transposed 256x256
constexpr size_t SB_OFF  = WS2_OFF + align_up(256 * 256 * 4);
constexpr size_t SUMS_OFF = SB_OFF + align_up(256 * 4);    // 8 layers x 64 floats
constexpr size_t PAR_OFF  = SUMS_OFF + align_up(8 * 64 * 4); // 9 slots x 64 floats
constexpr size_t CNT_OFF  = PAR_OFF + align_up(9 * 64 * 4);
constexpr size_t ROW_OFF  = CNT_OFF + align_up((size_t)N * 4);
constexpr size_t FILL_OFF = ROW_OFF + align_up((size_t)(N + 1) * 4);
constexpr size_t COL_OFF  = FILL_OFF + align_up((size_t)N * 4);
constexpr size_t DEG_OFF  = COL_OFF + align_up((size_t)E * 4);
// aliases used after all layers are done:
constexpr size_t S_OFF  = C2_OFF;   // N*256 floats
constexpr size_t Y1_OFF = H_OFF;    // N*512 floats (spans H+C1)

// ---------------- CSR build ----------------
__global__ void k_count(const int* __restrict__ dst, int* __restrict__ cnt) {
  int i = blockIdx.x * 256 + threadIdx.x;
  if (i < E) atomicAdd(&cnt[dst[i]], 1);
}

__global__ __launch_bounds__(256) void k_scan(const int* __restrict__ cnt, int* __restrict__ rowptr,
                                              int* __restrict__ fill, float* __restrict__ deginv) {
  __shared__ int sc[256];
  int tid = threadIdx.x;
  constexpr int CH = (N + 255) / 256;
  int start = tid * CH;
  int s = 0;
  for (int i = 0; i < CH; i++) { int idx = start + i; if (idx < N) s += cnt[idx]; }
  sc[tid] = s; __syncthreads();
  for (int off = 1; off < 256; off <<= 1) {
    int v = (tid >= off) ? sc[tid - off] : 0;
    __syncthreads();
    sc[tid] += v;
    __syncthreads();
  }
  int run = (tid == 0) ? 0 : sc[tid - 1];
  for (int i = 0; i < CH; i++) {
    int idx = start + i;
    if (idx < N) {
      int v = cnt[idx];
      rowptr[idx] = run; fill[idx] = run;
      deginv[idx] = 1.0f / (float)(v > 1 ? v : 1);
      run += v;
    }
  }
  if (tid == 255) rowptr[N] = run;
}

__global__ void k_scatter(const int* __restrict__ src, const int* __restrict__ dst,
                          int* __restrict__ fill, int* __restrict__ col) {
  int i = blockIdx.x * 256 + threadIdx.x;
  if (i < E) { int d = dst[i]; int p = atomicAdd(&fill[d], 1); col[p] = src[i]; }
}

__global__ void k_init_params(float* __restrict__ par) {
  int i = threadIdx.x;                 // 64 threads: slot 0 = identity affine
  par[i] = (i < 32) ? 1.0f : 0.0f;
}

// ---------------- enter 1x1 conv: inputs [N,T,3] -> x bf16 [n][t][c] ----------------
__global__ void k_enter(const float* __restrict__ in, const float* __restrict__ w,
                        const float* __restrict__ b, uint32* __restrict__ x) {
  int idx = blockIdx.x * 256 + threadIdx.x;     // word index; word = 2 channels
  if (idx >= N * 13 * 16) return;
  int cw = idx & 15; int tmp = idx >> 4; int t = tmp % 13; int n = tmp / 13;
  int c0 = cw * 2;
  const float* ip = in + (size_t)n * (13 * 3) + t * 3;
  float v0 = b[c0]     + w[c0 * 3 + 0]       * ip[0] + w[c0 * 3 + 1]       * ip[1] + w[c0 * 3 + 2]       * ip[2];
  float v1 = b[c0 + 1] + w[(c0 + 1) * 3 + 0] * ip[0] + w[(c0 + 1) * 3 + 1] * ip[1] + w[(c0 + 1) * 3 + 2] * ip[2];
  x[idx] = packbf(v0, v1);
}

// ---------------- gated dilated conv v3: LDS x-stage transposed [c][t], b128 broadcast reads ----------------
template <int TIN, int TOUT, int D>
__global__ __launch_bounds__(256, 4) void k_conv(const uint32* __restrict__ x,
    const float* __restrict__ fw, const float* __restrict__ fb,
    const float* __restrict__ gw, const float* __restrict__ gb,
    const float* __restrict__ par, int slot, int layer,
    unsigned short* __restrict__ h, float* __restrict__ hlast) {
  constexpr int TP = (TIN + 3) & ~3;              // padded t-stride (16B-aligned rows)
  __shared__ float wf[64 * 33], wg[64 * 33];      // [2i+k][o] padded stride 33
  __shared__ float xs[8][32 * TP];                // [n][c][t]
  int tx = threadIdx.x, ty = threadIdx.y;
  int tid = ty * 32 + tx;
  const float* fwl = fw + (size_t)layer * 2048;   // [o][i][k] linear = o*64 + 2i + k
  const float* gwl = gw + (size_t)layer * 2048;
  for (int i = tid; i < 2048; i += 256) {
    int o = i >> 6, r = i & 63;
    wf[r * 33 + o] = fwl[i];
    wg[r * 33 + o] = gwl[i];
  }
  int n0 = blockIdx.x * 8;
  const float* scp = par + slot * 64;
  for (int i = tid; i < 8 * TIN * 16; i += 256) {   // word granularity (2ch/word)
    int nl = i / (TIN * 16), rem = i % (TIN * 16);
    int cw = rem & 15; int c0 = cw * 2; int t = rem >> 4;
    int gn = n0 + nl;
    uint32 v = (gn < N) ? x[(size_t)gn * (TIN * 16) + rem] : 0u;
    float f0 = (gn < N) ? (scp[c0] * bflo(v) + scp[32 + c0]) : 0.0f;
    float f1 = (gn < N) ? (scp[c0 + 1] * bfhi(v) + scp[32 + c0 + 1]) : 0.0f;
    xs[nl][c0 * TP + t] = f0;
    xs[nl][(c0 + 1) * TP + t] = f1;
  }
  __syncthreads();
  int o = tx, nn = ty, n = n0 + nn;
  float accF[TOUT], accG[TOUT];
  float fbv = fb[layer * 32 + o], gbv = gb[layer * 32 + o];
#pragma unroll
  for (int t = 0; t < TOUT; t++) { accF[t] = fbv; accG[t] = gbv; }
#pragma unroll 4
  for (int i = 0; i < 32; i++) {
    float xv[TIN];
#pragma unroll
    for (int t = 0; t < TIN; t++) xv[t] = xs[nn][i * TP + t];   // contiguous -> b128 broadcast
    float w0 = wf[(2 * i) * 33 + o], w1 = wf[(2 * i + 1) * 33 + o];
    float g0 = wg[(2 * i) * 33 + o], g1 = wg[(2 * i + 1) * 33 + o];
#pragma unroll
    for (int t = 0; t < TOUT; t++) {
      accF[t] += w0 * xv[t] + w1 * xv[t + D];
      accG[t] += g0 * xv[t] + g1 * xv[t + D];
    }
  }
  if (n < N) {
#pragma unroll
    for (int t = 0; t < TOUT; t++) {
      float f = accF[t];
      float af = fabsf(f);
      float ef = __expf(-2.0f * af);
      float th = (1.0f - ef) / (1.0f + ef);
      th = copysignf(th, f);
      float sg = 1.0f / (1.0f + __expf(-accG[t]));
      float hv = th * sg;
      h[(size_t)n * (TOUT * 32) + t * 32 + o] = f2bf(hv);
      if (t == TOUT - 1) hlast[(size_t)n * 256 + layer * 32 + o] = hv;
    }
  }
}

// ---------------- one diffusion hop (bf16, fp32 accumulate, x8 edge unroll) ----------------
template <int F>
__global__ __launch_bounds__(256) void k_hop(const uint32* __restrict__ in, uint32* __restrict__ out,
    const int* __restrict__ rowptr, const int* __restrict__ col, const float* __restrict__ deginv) {
  constexpr int F2 = F / 2;                 // uint words per row
  constexpr int NW = (F2 + 63) / 64;
  int wid = (blockIdx.x * 256 + threadIdx.x) >> 6;   // one wave per node
  int lane = threadIdx.x & 63;
  if (wid >= N) return;
  int s = rowptr[wid], e = rowptr[wid + 1];
  float alo[NW], ahi[NW];
#pragma unroll
  for (int k = 0; k < NW; k++) { alo[k] = 0.0f; ahi[k] = 0.0f; }
  int idx = s;
  for (; idx + 7 < e; idx += 8) {
    const uint32* p[8];
#pragma unroll
    for (int q = 0; q < 8; q++) p[q] = in + (size_t)col[idx + q] * F2;
    uint32 v[8][NW];
#pragma unroll
    for (int q = 0; q < 8; q++) {
#pragma unroll
      for (int k = 0; k < NW; k++) {
        int j = k * 64 + lane;
        v[q][k] = (j < F2) ? p[q][j] : 0u;
      }
    }
#pragma unroll
    for (int k = 0; k < NW; k++) {
      alo[k] += ((bflo(v[0][k]) + bflo(v[1][k])) + (bflo(v[2][k]) + bflo(v[3][k]))) +
                ((bflo(v[4][k]) + bflo(v[5][k])) + (bflo(v[6][k]) + bflo(v[7][k])));
      ahi[k] += ((bfhi(v[0][k]) + bfhi(v[1][k])) + (bfhi(v[2][k]) + bfhi(v[3][k]))) +
                ((bfhi(v[4][k]) + bfhi(v[5][k])) + (bfhi(v[6][k]) + bfhi(v[7][k])));
    }
  }
  for (; idx + 3 < e; idx += 4) {
    const uint32* p0 = in + (size_t)col[idx] * F2;
    const uint32* p1 = in + (size_t)col[idx + 1] * F2;
    const uint32* p2 = in + (size_t)col[idx + 2] * F2;
    const uint32* p3 = in + (size_t)col[idx + 3] * F2;
#pragma unroll
    for (int k = 0; k < NW; k++) {
      int j = k * 64 + lane;
      if (j < F2) {
        uint32 v0 = p0[j], v1 = p1[j], v2 = p2[j], v3 = p3[j];
        alo[k] += (bflo(v0) + bflo(v1)) + (bflo(v2) + bflo(v3));
        ahi[k] += (bfhi(v0) + bfhi(v1)) + (bfhi(v2) + bfhi(v3));
      }
    }
  }
  for (; idx < e; ++idx) {
    const uint32* p = in + (size_t)col[idx] * F2;
#pragma unroll
    for (int k = 0; k < NW; k++) {
      int j = k * 64 + lane;
      if (j < F2) { uint32 v = p[j]; alo[k] += bflo(v); ahi[k] += bfhi(v); }
    }
  }
  float inv = deginv[wid];
  uint32* q = out + (size_t)wid * F2;
#pragma unroll
  for (int k = 0; k < NW; k++) {
    int j = k * 64 + lane;
    if (j < F2) q[j] = packbf(alo[k] * inv, ahi[k] * inv);
  }
}

// ---------------- combine: bf16 IO; LDS access in proven 0-conflict float2 patterns ----------------
template <int TIN, int TOUT>
__global__ __launch_bounds__(256) void k_combine(const uint32* __restrict__ h,
    const uint32* __restrict__ c1, const uint32* __restrict__ c2, const uint32* __restrict__ c3,
    const float* __restrict__ gcw, const float* __restrict__ gcb,
    const uint32* __restrict__ xcur, int layer,
    const float* __restrict__ par, int slot,
    uint32* __restrict__ xnext, float* __restrict__ sums) {
  constexpr int RS = 34;                 // LDS row stride (floats)
  __shared__ float ws[4096];             // [k][c][o]
  __shared__ float xst[128 * RS];        // staging
  __shared__ float pbuf[96];             // gcb[32], psc[32], psh[32]
  __shared__ float r1s[32], r2s[32];
  int tid = threadIdx.x;
  const float* wsrc = gcw + (size_t)layer * 4096;
  for (int i = tid; i < 4096; i += 256) ws[i] = wsrc[i];
  if (tid < 32) {
    pbuf[tid]      = gcb[layer * 32 + tid];
    pbuf[32 + tid] = par[slot * 64 + tid];
    pbuf[64 + tid] = par[slot * 64 + 32 + tid];
    r1s[tid] = 0.0f; r2s[tid] = 0.0f;
  }

  int nrows = N * TOUT;
  int base = blockIdx.x * 128;
  int rg = tid >> 3, oq = tid & 7;       // rg: 0..31, oq: 0..7 (outs oq*4..+4)

  float acc[4][4];
#pragma unroll
  for (int i = 0; i < 4; i++)
#pragma unroll
    for (int j = 0; j < 4; j++) acc[i][j] = 0.0f;

  const uint32* srcs[4] = { h, c1, c2, c3 };
#pragma unroll 1
  for (int k = 0; k < 4; k++) {
    const uint32* src = srcs[k];
    __syncthreads();                     // xst free (also covers r1s init on k==0)
    const uint4* gp = (const uint4*)src;  // one uint4 = 8 bf16 channels
#pragma unroll
    for (int it = 0; it < 2; it++) {
      int l = it * 256 + tid;            // 512 uint4 = 128 rows
      int g = base * 4 + l;
      uint4 v = make_uint4(0u, 0u, 0u, 0u);
      if (g < nrows * 4) v = gp[g];
      int rl = l >> 2, q4 = l & 3;
      float* dst = &xst[rl * RS + q4 * 8];
      dst[0] = bflo(v.x); dst[1] = bfhi(v.x);
      dst[2] = bflo(v.y); dst[3] = bfhi(v.y);
      dst[4] = bflo(v.z); dst[5] = bfhi(v.z);
      dst[6] = bflo(v.w); dst[7] = bfhi(v.w);
    }
    __syncthreads();
    const float* wk = &ws[k * 1024];
#pragma unroll 4
    for (int c2i = 0; c2i < 16; c2i++) {
      int c = c2i * 2;
      float4 w0 = *(const float4*)&wk[c * 32 + oq * 4];
      float4 w1 = *(const float4*)&wk[(c + 1) * 32 + oq * 4];
#pragma unroll
      for (int i = 0; i < 4; i++) {
        float2 xv = *(const float2*)&xst[(rg + 32 * i) * RS + c];
        acc[i][0] += xv.x * w0.x + xv.y * w1.x;
        acc[i][1] += xv.x * w0.y + xv.y * w1.y;
        acc[i][2] += xv.x * w0.z + xv.y * w1.z;
        acc[i][3] += xv.x * w0.w + xv.y * w1.w;
      }
    }
  }

  // stage residual rows (bf16 -> fp32) in the v6 float2 pattern (0-conflict)
  constexpr int toff = TIN - TOUT;
  __syncthreads();
  {
#pragma unroll
    for (int it = 0; it < 4; it++) {
      int l = it * 256 + tid;            // 1024 = 128 rows x 8 word-pairs
      int rrow = base + (l >> 3);
      int j4 = l & 7;
      if (rrow < nrows) {
        int n = rrow / TOUT, t = rrow - n * TOUT;
        const uint32* rp = xcur + ((size_t)n * TIN + toff + t) * 16 + j4 * 2;
        uint32 va = rp[0], vb = rp[1];
        int rl = l >> 3;
        *(float2*)&xst[rl * RS + j4 * 4]     = make_float2(bflo(va), bfhi(va));
        *(float2*)&xst[rl * RS + j4 * 4 + 2] = make_float2(bflo(vb), bfhi(vb));
      }
    }
  }
  __syncthreads();

  // vout = acc + gcb + psc*xr + psh; BN partials; write back into private xst slots
  float gb0 = pbuf[oq * 4 + 0], gb1 = pbuf[oq * 4 + 1], gb2 = pbuf[oq * 4 + 2], gb3 = pbuf[oq * 4 + 3];
  float sc0 = pbuf[32 + oq * 4 + 0], sc1 = pbuf[32 + oq * 4 + 1], sc2 = pbuf[32 + oq * 4 + 2], sc3 = pbuf[32 + oq * 4 + 3];
  float sh0 = pbuf[64 + oq * 4 + 0], sh1 = pbuf[64 + oq * 4 + 1], sh2 = pbuf[64 + oq * 4 + 2], sh3 = pbuf[64 + oq * 4 + 3];
  float s1[4] = {0.f, 0.f, 0.f, 0.f}, s2[4] = {0.f, 0.f, 0.f, 0.f};
#pragma unroll
  for (int i = 0; i < 4; i++) {
    int r = rg + 32 * i;
    bool act = (base + r) < nrows;
    float2 xa = *(const float2*)&xst[r * RS + oq * 4];
    float2 xb = *(const float2*)&xst[r * RS + oq * 4 + 2];
    float v0 = acc[i][0] + gb0 + sc0 * xa.x + sh0;
    float v1 = acc[i][1] + gb1 + sc1 * xa.y + sh1;
    float v2 = acc[i][2] + gb2 + sc2 * xb.x + sh2;
    float v3 = acc[i][3] + gb3 + sc3 * xb.y + sh3;
    *(float2*)&xst[r * RS + oq * 4]     = make_float2(v0, v1);
    *(float2*)&xst[r * RS + oq * 4 + 2] = make_float2(v2, v3);
    if (act) {
      s1[0] += v0; s1[1] += v1; s1[2] += v2; s1[3] += v3;
      s2[0] += v0 * v0; s2[1] += v1 * v1; s2[2] += v2 * v2; s2[3] += v3 * v3;
    }
  }
#pragma unroll
  for (int j = 0; j < 4; j++) {
    atomicAdd(&r1s[oq * 4 + j], s1[j]);
    atomicAdd(&r2s[oq * 4 + j], s2[j]);
  }
  __syncthreads();

  // cooperative coalesced output store (fp32 LDS -> bf16 global), v6 read pattern
  {
    uint2* outp = (uint2*)xnext;
#pragma unroll
    for (int it = 0; it < 4; it++) {
      int l = it * 256 + tid;            // 1024 uint2 = 128 rows x 16 words
      int g = base * 8 + l;              // uint2 index
      if (g < nrows * 8) {
        int rl = l >> 3, j4 = l & 7;
        float2 a = *(const float2*)&xst[rl * RS + j4 * 4];
        float2 b = *(const float2*)&xst[rl * RS + j4 * 4 + 2];
        outp[g] = make_uint2(packbf(a.x, a.y), packbf(b.x, b.y));
      }
    }
  }
  if (tid < 32) atomicAdd(&sums[layer * 64 + tid], r1s[tid]);
  else if (tid < 64) atomicAdd(&sums[layer * 64 + tid], r2s[tid - 32]);
}

// ---------------- BN stats -> affine params for next slot ----------------
__global__ void k_bnfin(const float* __restrict__ sums, const float* __restrict__ bng,
                        const float* __restrict__ bnb, float* __restrict__ par,
                        int layer, int tout) {
  int o = threadIdx.x;  // 32
  float cnt = (float)N * (float)tout;
  float s1 = sums[layer * 64 + o], s2 = sums[layer * 64 + 32 + o];
  float mu = s1 / cnt;
  float var = s2 / cnt - mu * mu;
  float sc = bng[layer * 32 + o] * rsqrtf(var + 1e-5f);
  par[(layer + 1) * 64 + o] = sc;
  par[(layer + 1) * 64 + 32 + o] = bnb[layer * 32 + o] - mu * sc;
}

// ---------------- head prep ----------------
__global__ void k_prep_skipw(const float* __restrict__ sw, float* __restrict__ w2) {
  int idx = blockIdx.x * 256 + threadIdx.x;
  if (idx >= 8 * 256 * 32) return;
  int l = idx / (256 * 32), r = idx % (256 * 32), o = r / 32, c = r & 31;
  w2[o * 256 + l * 32 + c] = sw[idx];
}
__global__ void k_prep_sb(const float* __restrict__ sb, float* __restrict__ out) {
  int o = threadIdx.x;  // 256
  float s = 0.0f;
  for (int l = 0; l < 8; l++) s += sb[l * 256 + o];
  out[o] = s;
}

// ---------------- generic tiled fp32 GEMM: C[M,O] = act(A[M,K] @ W[O,K]^T + bias) ----------------
__global__ __launch_bounds__(256) void k_gemm(const float* __restrict__ A, const float* __restrict__ W,
    const float* __restrict__ bias, float* __restrict__ Cout,
    int M, int K, int Onum, int relu) {
  __shared__ float As[16][68];
  __shared__ float Wsh[16][68];
  int tid = threadIdx.x;
  int bm = blockIdx.x * 64, bo = blockIdx.y * 64;
  int tm = (tid >> 4) << 2, to = (tid & 15) << 2;
  float acc[4][4] = {};
  int lm = tid >> 2, kq = (tid & 3) << 2;
  for (int k0 = 0; k0 < K; k0 += 16) {
    float4 av = make_float4(0.f, 0.f, 0.f, 0.f);
    int gm = bm + lm;
    if (gm < M) av = *(const float4*)(A + (size_t)gm * K + k0 + kq);
    As[kq + 0][lm] = av.x; As[kq + 1][lm] = av.y; As[kq + 2][lm] = av.z; As[kq + 3][lm] = av.w;
    float4 wv = *(const float4*)(W + (size_t)(bo + lm) * K + k0 + kq);
    Wsh[kq + 0][lm] = wv.x; Wsh[kq + 1][lm] = wv.y; Wsh[kq + 2][lm] = wv.z; Wsh[kq + 3][lm] = wv.w;
    __syncthreads();
#pragma unroll
    for (int k = 0; k < 16; k++) {
      float am[4], wn[4];
#pragma unroll
      for (int j = 0; j < 4; j++) { am[j] = As[k][tm + j]; wn[j] = Wsh[k][to + j]; }
#pragma unroll
      for (int i = 0; i < 4; i++)
#pragma unroll
        for (int j = 0; j < 4; j++) acc[i][j] += am[i] * wn[j];
    }
    __syncthreads();
  }
#pragma unroll
  for (int i = 0; i < 4; i++) {
    int gm = bm + tm + i; if (gm >= M) continue;
#pragma unroll
    for (int j = 0; j < 4; j++) {
      int go = bo + to + j;
      float v = acc[i][j] + bias[go];
      if (relu) v = fmaxf(v, 0.0f);
      Cout[(size_t)gm * Onum + go] = v;
    }
  }
}

// ---------------- final: K-split tiled GEMM with atomic reduce -> d_out [N,24] ----------------
__global__ __launch_bounds__(256) void k_final2(const float* __restrict__ Y1, const float* __restrict__ W2,
                                                const float* __restrict__ b2, float* __restrict__ out) {
  __shared__ float y1s[64][68];
  __shared__ float w2s[24][65];
  int tid = threadIdx.x;
  int bm = blockIdx.x * 64;
  int k0 = blockIdx.y * 64;
  for (int i = tid; i < 64 * 16; i += 256) {
    int r = i >> 4, k4 = i & 15;
    int gm = bm + r;
    float4 v = make_float4(0.f, 0.f, 0.f, 0.f);
    if (gm < N) v = *(const float4*)(Y1 + (size_t)gm * 512 + k0 + k4 * 4);
    y1s[r][k4 * 4 + 0] = v.x; y1s[r][k4 * 4 + 1] = v.y;
    y1s[r][k4 * 4 + 2] = v.z; y1s[r][k4 * 4 + 3] = v.w;
  }
  for (int i = tid; i < 24 * 16; i += 256) {
    int o = i >> 4, k4 = i & 15;
    float4 v = *(const float4*)(W2 + (size_t)o * 512 + k0 + k4 * 4);
    w2s[o][k4 * 4 + 0] = v.x; w2s[o][k4 * 4 + 1] = v.y;
    w2s[o][k4 * 4 + 2] = v.z; w2s[o][k4 * 4 + 3] = v.w;
  }
  __syncthreads();
  int rg = tid >> 5;        // 0..7 -> rows rg*8..+8
  int o = tid & 31;         // 0..31, active o<24
  if (o < 24) {
    float acc[8] = {};
    for (int kk = 0; kk < 64; kk++) {
      float w = w2s[o][kk];
#pragma unroll
      for (int i = 0; i < 8; i++) acc[i] += y1s[rg * 8 + i][kk] * w;
    }
    float bias = (blockIdx.y == 0) ? b2[o] : 0.0f;
#pragma unroll
    for (int i = 0; i < 8; i++) {
      int gm = bm + rg * 8 + i;
      if (gm < N) atomicAdd(&out[(size_t)gm * 24 + o], acc[i] + bias);
    }
  }
}

// ---------------- host side ----------------
struct Ptrs {
  const float *fw, *fb, *gw, *gb, *gcw, *gcb, *bng, *bnb;
  void *H, *C1, *C2, *C3;
  float *HL, *par, *sums;
  const int *row, *col;
  const float *deg;
};

template <int TIN, int TOUT, int D>
static void run_layer(int layer, bool last, const Ptrs& P, uint32*& xc, uint32*& xn, hipStream_t stream) {
  dim3 cb(32, 8);
  int blocks = (N + 7) / 8;
  k_conv<TIN, TOUT, D><<<blocks, cb, 0, stream>>>(xc, P.fw, P.fb, P.gw, P.gb, P.par, layer, layer,
                                                  (unsigned short*)P.H, P.HL);
  if (!last) {
    constexpr int F = TOUT * 32;
    int hb = (N * 64 + 255) / 256;
    k_hop<F><<<hb, 256, 0, stream>>>((const uint32*)P.H, (uint32*)P.C1, P.row, P.col, P.deg);
    k_hop<F><<<hb, 256, 0, stream>>>((const uint32*)P.C1, (uint32*)P.C2, P.row, P.col, P.deg);
    k_hop<F><<<hb, 256, 0, stream>>>((const uint32*)P.C2, (uint32*)P.C3, P.row, P.col, P.deg);
    int cblocks = (N * TOUT + 127) / 128;
    k_combine<TIN, TOUT><<<cblocks, 256, 0, stream>>>((const uint32*)P.H, (const uint32*)P.C1,
                                                      (const uint32*)P.C2, (const uint32*)P.C3,
                                                      P.gcw, P.gcb, xc, layer, P.par, layer, xn, P.sums);
    k_bnfin<<<1, 32, 0, stream>>>(P.sums, P.bng, P.bnb, P.par, layer, TOUT);
    uint32* tmp = xc; xc = xn; xn = tmp;
  }
}

extern "C" void kernel_launch(void* const* d_in, const int* in_sizes, int n_in,
                              void* d_out, int out_size, void* d_ws, size_t ws_size,
                              hipStream_t stream) {
  const float* inputs  = (const float*)d_in[0];
  const int*   esrc    = (const int*)d_in[1];
  const int*   edst    = (const int*)d_in[2];
  const float* enter_w = (const float*)d_in[3];
  const float* enter_b = (const float*)d_in[4];
  const float* filt_w  = (const float*)d_in[5];
  const float* filt_b  = (const float*)d_in[6];
  const float* gate_w  = (const float*)d_in[7];
  const float* gate_b  = (const float*)d_in[8];
  const float* gc_w    = (const float*)d_in[9];
  const float* gc_b    = (const float*)d_in[10];
  const float* skip_w  = (const float*)d_in[11];
  const float* skip_b  = (const float*)d_in[12];
  const float* bn_g    = (const float*)d_in[13];
  const float* bn_b    = (const float*)d_in[14];
  const float* out1_w  = (const float*)d_in[15];
  const float* out1_b  = (const float*)d_in[16];
  const float* out2_w  = (const float*)d_in[17];
  const float* out2_b  = (const float*)d_in[18];

  char* ws = (char*)d_ws;
  uint32* XA = (uint32*)(ws + XA_OFF);
  uint32* XB = (uint32*)(ws + XB_OFF);
  void* H    = (void*)(ws + H_OFF);
  void* C1   = (void*)(ws + C1_OFF);
  void* C2   = (void*)(ws + C2_OFF);
  void* C3   = (void*)(ws + C3_OFF);
  float* HL  = (float*)(ws + HL_OFF);
  float* WS2 = (float*)(ws + WS2_OFF);
  float* SB  = (float*)(ws + SB_OFF);
  float* SUMS = (float*)(ws + SUMS_OFF);
  float* PAR  = (float*)(ws + PAR_OFF);
  int* CNT  = (int*)(ws + CNT_OFF);
  int* ROW  = (int*)(ws + ROW_OFF);
  int* FILL = (int*)(ws + FILL_OFF);
  int* COL  = (int*)(ws + COL_OFF);
  float* DEG = (float*)(ws + DEG_OFF);
  float* S  = (float*)(ws + S_OFF);
  float* Y1 = (float*)(ws + Y1_OFF);

  hipMemsetAsync(CNT, 0, (size_t)N * 4, stream);
  hipMemsetAsync(SUMS, 0, 8 * 64 * 4, stream);
  hipMemsetAsync(d_out, 0, (size_t)out_size * 4, stream);

  k_count<<<(E + 255) / 256, 256, 0, stream>>>(edst, CNT);
  k_scan<<<1, 256, 0, stream>>>(CNT, ROW, FILL, DEG);
  k_scatter<<<(E + 255) / 256, 256, 0, stream>>>(esrc, edst, FILL, COL);
  k_init_params<<<1, 64, 0, stream>>>(PAR);
  k_enter<<<(N * 13 * 16 + 255) / 256, 256, 0, stream>>>(inputs, enter_w, enter_b, XA);
  k_prep_skipw<<<(8 * 256 * 32 + 255) / 256, 256, 0, stream>>>(skip_w, WS2);
  k_prep_sb<<<1, 256, 0, stream>>>(skip_b, SB);

  Ptrs P;
  P.fw = filt_w; P.fb = filt_b; P.gw = gate_w; P.gb = gate_b;
  P.gcw = gc_w; P.gcb = gc_b; P.bng = bn_g; P.bnb = bn_b;
  P.H = H; P.C1 = C1; P.C2 = C2; P.C3 = C3; P.HL = HL; P.par = PAR; P.sums = SUMS;
  P.row = ROW; P.col = COL; P.deg = DEG;

  uint32* xc = XA; uint32* xn = XB;
  run_layer<13, 12, 1>(0, false, P, xc, xn, stream);
  run_layer<12, 10, 2>(1, false, P, xc, xn, stream);
  run_layer<10, 9, 1>(2, false, P, xc, xn, stream);
  run_layer<9, 7, 2>(3, false, P, xc, xn, stream);
  run_layer<7, 6, 1>(4, false, P, xc, xn, stream);
  run_layer<6, 4, 2>(5, false, P, xc, xn, stream);
  run_layer<4, 3, 1>(6, false, P, xc, xn, stream);
  run_layer<3, 1, 2>(7, true, P, xc, xn, stream);

  // head: S = relu(HL @ WS2^T + SB); Y1 = relu(S @ out1_w^T + out1_b); out = Y1 @ out2_w^T + out2_b
  dim3 g1((N + 63) / 64, 256 / 64);
  k_gemm<<<g1, 256, 0, stream>>>(HL, WS2, SB, S, N, 256, 256, 1);
  dim3 g2((N + 63) / 64, 512 / 64);
  k_gemm<<<g2, 256, 0, stream>>>(S, out1_w, out1_b, Y1, N, 256, 512, 1);
  dim3 gf((N + 63) / 64, 8);
  k_final2<<<gf, 256, 0, stream>>>(Y1, out2_w, out2_b, (float*)d_out);
}